// Round 1
// baseline (538.478 us; speedup 1.0000x reference)
//
#include <hip/hip_runtime.h>

typedef unsigned short u16;
typedef __attribute__((ext_vector_type(8))) short short8;
typedef __attribute__((ext_vector_type(4))) float f32x4;

__device__ __forceinline__ float bf2f(u16 v) {
  union { unsigned int u; float f; } c; c.u = ((unsigned int)v) << 16; return c.f;
}
__device__ __forceinline__ u16 f2bf(float f) {
  union { float f; unsigned int u; } c; c.f = f;
  unsigned int u = c.u;
  return (u16)((u + 0x7fffu + ((u >> 16) & 1u)) >> 16);
}

// ---------------- prep: fp32 -> bf16 elementwise (n divisible by 1024) ----------------
__global__ __launch_bounds__(256) void cvt_f32_bf16(const float* __restrict__ in, u16* __restrict__ out) {
  size_t i = ((size_t)blockIdx.x * 256 + threadIdx.x) * 4;
  f32x4 v = *reinterpret_cast<const f32x4*>(&in[i]);
  unsigned int lo = (unsigned int)f2bf(v[0]) | ((unsigned int)f2bf(v[1]) << 16);
  unsigned int hi = (unsigned int)f2bf(v[2]) | ((unsigned int)f2bf(v[3]) << 16);
  unsigned long long p = ((unsigned long long)hi << 32) | lo;
  *reinterpret_cast<unsigned long long*>(&out[i]) = p;
}

// ---------------- prep: wq/wk/wv [H=16][C=1024][D=64] fp32 -> Wt[n=3072][c=1024] bf16 (B^T) ----
__global__ __launch_bounds__(256) void repack_w(const float* __restrict__ wq, const float* __restrict__ wk,
                                                const float* __restrict__ wv, u16* __restrict__ Wt) {
  int tid = blockIdx.x * 256 + threadIdx.x;   // 786432 total
  int dc = tid & 15;            // d-chunk of 4
  int c  = (tid >> 4) & 1023;
  int h  = (tid >> 14) & 15;
  int which = tid >> 18;        // 0..2
  const float* src = which == 0 ? wq : (which == 1 ? wk : wv);
  f32x4 v = *reinterpret_cast<const f32x4*>(&src[(size_t)h * 65536 + (size_t)c * 64 + dc * 4]);
  int nb = which * 1024 + h * 64 + dc * 4;
#pragma unroll
  for (int i = 0; i < 4; ++i)
    Wt[(size_t)(nb + i) * 1024 + c] = f2bf(v[i]);
}

// ---------------- GEMM: C[M,N] = A[M,K] * Bt[N,K]^T (+bias), bf16 in, fp32 acc ----------------
// 128x128 tile, 4 waves of 64x64, BK=32, global_load_lds staging (m97 structure)
template<bool BIAS, bool BF16_OUT>
__global__ __launch_bounds__(256)
void gemm_bt(const u16* __restrict__ A, const u16* __restrict__ Bt,
             const float* __restrict__ bias, void* __restrict__ Cout,
             int M, int N, int K)
{
  __shared__ u16 As[128 * 32];
  __shared__ u16 Bs[128 * 32];
  const int tid  = threadIdx.x;
  const int wave = tid >> 6, lane = tid & 63;
  const int l15 = lane & 15, l4 = lane >> 4;
  const int row0 = blockIdx.x * 128, col0 = blockIdx.y * 128;
  const int wr = (wave >> 1) * 64, wc = (wave & 1) * 64;

  f32x4 acc[4][4] = {};

  const int i0 = tid, i1 = tid + 256;
  const int ar0 = i0 >> 2, ac0 = (i0 & 3) * 8;
  const int ar1 = i1 >> 2, ac1 = (i1 & 3) * 8;

  for (int k0 = 0; k0 < K; k0 += 32) {
    __builtin_amdgcn_global_load_lds(
      (const __attribute__((address_space(1))) void*)(A + (size_t)(row0 + ar0) * K + k0 + ac0),
      (__attribute__((address_space(3))) void*)(As + wave * 512), 16, 0, 0);
    __builtin_amdgcn_global_load_lds(
      (const __attribute__((address_space(1))) void*)(A + (size_t)(row0 + ar1) * K + k0 + ac1),
      (__attribute__((address_space(3))) void*)(As + 2048 + wave * 512), 16, 0, 0);
    __builtin_amdgcn_global_load_lds(
      (const __attribute__((address_space(1))) void*)(Bt + (size_t)(col0 + ar0) * K + k0 + ac0),
      (__attribute__((address_space(3))) void*)(Bs + wave * 512), 16, 0, 0);
    __builtin_amdgcn_global_load_lds(
      (const __attribute__((address_space(1))) void*)(Bt + (size_t)(col0 + ar1) * K + k0 + ac1),
      (__attribute__((address_space(3))) void*)(Bs + 2048 + wave * 512), 16, 0, 0);
    __syncthreads();

    short8 af[4], bfr[4];
#pragma unroll
    for (int m = 0; m < 4; ++m)
      af[m] = *reinterpret_cast<const short8*>(&As[(wr + m * 16 + l15) * 32 + l4 * 8]);
#pragma unroll
    for (int n = 0; n < 4; ++n)
      bfr[n] = *reinterpret_cast<const short8*>(&Bs[(wc + n * 16 + l15) * 32 + l4 * 8]);
#pragma unroll
    for (int m = 0; m < 4; ++m)
#pragma unroll
      for (int n = 0; n < 4; ++n)
        acc[m][n] = __builtin_amdgcn_mfma_f32_16x16x32_bf16(af[m], bfr[n], acc[m][n], 0, 0, 0);
    __syncthreads();
  }

  u16* Cb = (u16*)Cout;
  float* Cf = (float*)Cout;
#pragma unroll
  for (int n = 0; n < 4; ++n) {
    const int c = col0 + wc + n * 16 + l15;
    const float bv = BIAS ? bias[c] : 0.0f;
#pragma unroll
    for (int m = 0; m < 4; ++m) {
      const int r0 = row0 + wr + m * 16 + l4 * 4;
#pragma unroll
      for (int r = 0; r < 4; ++r) {
        float v = acc[m][n][r] + bv;
        if (BF16_OUT) Cb[(size_t)(r0 + r) * N + c] = f2bf(v);
        else          Cf[(size_t)(r0 + r) * N + c] = v;
      }
    }
  }
}

// ---------------- flash attention ----------------
// QKV layout: [B*T][3072] bf16, q at col h*64, k at 1024+h*64, v at 2048+h*64
// grid (T/64, B*H), 256 thr = 4 waves, wave handles 16 queries; KV blocks of 64, causal skip kvb<=qb
__global__ __launch_bounds__(256)
void attn_kernel(const u16* __restrict__ qkv, u16* __restrict__ att)
{
  const int T = 2048, C3 = 3072;
  const int qb = blockIdx.x;          // 0..31
  const int bh = blockIdx.y;          // 0..63
  const int b = bh >> 4, h = bh & 15;
  const int tid = threadIdx.x, wave = tid >> 6, lane = tid & 63;
  const int l15 = lane & 15, l4 = lane >> 4;

  __shared__ u16 Ks[64][72];      // K tile [s][d], padded (ds_write staged, pad OK)
  __shared__ u16 Vt[64][72];      // V^T tile [d][s]
  __shared__ u16 Ps[4][16][72];   // per-wave P tile [t][s]

  const size_t base = (size_t)b * T * C3 + (size_t)h * 64;
  const u16* qp = qkv + base;
  const u16* kp = qkv + base + 1024;
  const u16* vp = qkv + base + 2048;

  // Q fragments (A-layout: row=l&15, k=(l>>4)*8+i), prescaled by 1/32 (exact pow2)
  const int tq = qb * 64 + wave * 16 + l15;
  short8 qf[2];
#pragma unroll
  for (int kk = 0; kk < 2; ++kk) {
    short8 v = *reinterpret_cast<const short8*>(&qp[(size_t)tq * C3 + kk * 32 + l4 * 8]);
#pragma unroll
    for (int i = 0; i < 8; ++i) {
      u16 raw = (u16)v[i];
      v[i] = (short)f2bf(bf2f(raw) * 0.03125f);
    }
    qf[kk] = v;
  }

  f32x4 o[4] = {};
  float mrun[4] = {-1e30f, -1e30f, -1e30f, -1e30f};
  float lrun[4] = {};

  for (int kvb = 0; kvb <= qb; ++kvb) {
    __syncthreads();   // prev iteration's PV reads done before restage
    // stage K tile and transposed V tile
#pragma unroll
    for (int it = 0; it < 2; ++it) {
      const int idx = it * 256 + tid;
      const int row = idx >> 3, cc = idx & 7;
      const size_t goff = (size_t)(kvb * 64 + row) * C3 + cc * 8;
      short8 kv = *reinterpret_cast<const short8*>(&kp[goff]);
      *reinterpret_cast<short8*>(&Ks[row][cc * 8]) = kv;
      short8 vv = *reinterpret_cast<const short8*>(&vp[goff]);
#pragma unroll
      for (int i = 0; i < 8; ++i) Vt[cc * 8 + i][row] = (u16)vv[i];
    }
    __syncthreads();

    // S = (Q*scale) K^T   [16 queries x 64 keys per wave]
    f32x4 s[4] = {};
#pragma unroll
    for (int n = 0; n < 4; ++n)
#pragma unroll
      for (int kk = 0; kk < 2; ++kk) {
        short8 b8 = *reinterpret_cast<const short8*>(&Ks[n * 16 + l15][kk * 32 + l4 * 8]);
        s[n] = __builtin_amdgcn_mfma_f32_16x16x32_bf16(qf[kk], b8, s[n], 0, 0, 0);
      }

    // causal mask (diagonal block only)
    if (kvb == qb) {
#pragma unroll
      for (int n = 0; n < 4; ++n)
#pragma unroll
        for (int r = 0; r < 4; ++r) {
          int sk = kvb * 64 + n * 16 + l15;
          int tr = qb * 64 + wave * 16 + l4 * 4 + r;
          if (sk > tr) s[n][r] = -1e30f;
        }
    }

    // row max over 4 n-blocks + 16 lanes
    float mb[4];
#pragma unroll
    for (int r = 0; r < 4; ++r)
      mb[r] = fmaxf(fmaxf(s[0][r], s[1][r]), fmaxf(s[2][r], s[3][r]));
#pragma unroll
    for (int xm = 1; xm <= 8; xm <<= 1)
#pragma unroll
      for (int r = 0; r < 4; ++r)
        mb[r] = fmaxf(mb[r], __shfl_xor(mb[r], xm));

    float alpha[4];
#pragma unroll
    for (int r = 0; r < 4; ++r) {
      float mn = fmaxf(mrun[r], mb[r]);
      alpha[r] = __expf(mrun[r] - mn);
      mrun[r] = mn;
    }

    // p = exp(s - m), row sums, stage P (bf16) to per-wave LDS
    float rs[4] = {};
#pragma unroll
    for (int n = 0; n < 4; ++n)
#pragma unroll
      for (int r = 0; r < 4; ++r) {
        float p = __expf(s[n][r] - mrun[r]);
        rs[r] += p;
        Ps[wave][l4 * 4 + r][n * 16 + l15] = f2bf(p);
      }
#pragma unroll
    for (int xm = 1; xm <= 8; xm <<= 1)
#pragma unroll
      for (int r = 0; r < 4; ++r)
        rs[r] += __shfl_xor(rs[r], xm);
#pragma unroll
    for (int r = 0; r < 4; ++r)
      lrun[r] = lrun[r] * alpha[r] + rs[r];
#pragma unroll
    for (int db = 0; db < 4; ++db)
#pragma unroll
      for (int r = 0; r < 4; ++r)
        o[db][r] *= alpha[r];

    __syncthreads();   // P visible (and keeps Vt reads ordered vs this iter's writes)

    // O += P V
#pragma unroll
    for (int kk = 0; kk < 2; ++kk) {
      short8 a8 = *reinterpret_cast<const short8*>(&Ps[wave][l15][kk * 32 + l4 * 8]);
#pragma unroll
      for (int db = 0; db < 4; ++db) {
        short8 b8 = *reinterpret_cast<const short8*>(&Vt[db * 16 + l15][kk * 32 + l4 * 8]);
        o[db] = __builtin_amdgcn_mfma_f32_16x16x32_bf16(a8, b8, o[db], 0, 0, 0);
      }
    }
  }

  // normalize + write att[b*T+t][h*64+d] (concat-head layout)
#pragma unroll
  for (int db = 0; db < 4; ++db)
#pragma unroll
    for (int r = 0; r < 4; ++r) {
      int t = qb * 64 + wave * 16 + l4 * 4 + r;
      float val = o[db][r] / lrun[r];
      att[(size_t)(b * T + t) * 1024 + h * 64 + db * 16 + l15] = f2bf(val);
    }
}

// ---------------- launch ----------------
extern "C" void kernel_launch(void* const* d_in, const int* in_sizes, int n_in,
                              void* d_out, int out_size, void* d_ws, size_t ws_size,
                              hipStream_t stream)
{
  const float* x  = (const float*)d_in[0];
  const float* wq = (const float*)d_in[1];
  const float* wk = (const float*)d_in[2];
  const float* wv = (const float*)d_in[3];
  const float* wp = (const float*)d_in[4];
  const float* bp = (const float*)d_in[5];
  float* out = (float*)d_out;

  u16* xb  = (u16*)d_ws;                       // 8192*1024
  u16* Wt  = xb  + (size_t)8192 * 1024;        // 3072*1024
  u16* wpb = Wt  + (size_t)3072 * 1024;        // 1024*1024
  u16* QKV = wpb + (size_t)1024 * 1024;        // 8192*3072
  u16* att = QKV + (size_t)8192 * 3072;        // 8192*1024
  // total ws: 46.1M u16 = 92.3 MB

  cvt_f32_bf16<<<8192, 256, 0, stream>>>(x, xb);
  cvt_f32_bf16<<<1024, 256, 0, stream>>>(wp, wpb);
  repack_w<<<3072, 256, 0, stream>>>(wq, wk, wv, Wt);
  gemm_bt<false, true><<<dim3(64, 24), 256, 0, stream>>>(xb, Wt, nullptr, QKV, 8192, 3072, 1024);
  attn_kernel<<<dim3(32, 64), 256, 0, stream>>>(QKV, att);
  gemm_bt<true, false><<<dim3(64, 8), 256, 0, stream>>>(att, wpb, bp, out, 8192, 1024, 1024);
}

// Round 3
// 441.306 us; speedup vs baseline: 1.2202x; 1.2202x over previous
//
#include <hip/hip_runtime.h>

typedef unsigned short u16;
typedef __attribute__((ext_vector_type(8))) short short8;
typedef __attribute__((ext_vector_type(4))) float f32x4;

__device__ __forceinline__ float bf2f(u16 v) {
  union { unsigned int u; float f; } c; c.u = ((unsigned int)v) << 16; return c.f;
}
__device__ __forceinline__ u16 f2bf(float f) {
  union { float f; unsigned int u; } c; c.f = f;
  unsigned int u = c.u;
  return (u16)((u + 0x7fffu + ((u >> 16) & 1u)) >> 16);
}

// ---------------- prep: fp32 -> bf16 elementwise (n divisible by 1024) ----------------
__global__ __launch_bounds__(256) void cvt_f32_bf16(const float* __restrict__ in, u16* __restrict__ out) {
  size_t i = ((size_t)blockIdx.x * 256 + threadIdx.x) * 4;
  f32x4 v = *reinterpret_cast<const f32x4*>(&in[i]);
  unsigned int lo = (unsigned int)f2bf(v[0]) | ((unsigned int)f2bf(v[1]) << 16);
  unsigned int hi = (unsigned int)f2bf(v[2]) | ((unsigned int)f2bf(v[3]) << 16);
  unsigned long long p = ((unsigned long long)hi << 32) | lo;
  *reinterpret_cast<unsigned long long*>(&out[i]) = p;
}

// ---------------- prep: wq/wk/wv [H=16][C=1024][D=64] fp32 -> Wt[n=3072][c=1024] bf16 (B^T) ----
__global__ __launch_bounds__(256) void repack_w(const float* __restrict__ wq, const float* __restrict__ wk,
                                                const float* __restrict__ wv, u16* __restrict__ Wt) {
  int tid = blockIdx.x * 256 + threadIdx.x;   // 786432 total
  int dc = tid & 15;            // d-chunk of 4
  int c  = (tid >> 4) & 1023;
  int h  = (tid >> 14) & 15;
  int which = tid >> 18;        // 0..2
  const float* src = which == 0 ? wq : (which == 1 ? wk : wv);
  f32x4 v = *reinterpret_cast<const f32x4*>(&src[(size_t)h * 65536 + (size_t)c * 64 + dc * 4]);
  int nb = which * 1024 + h * 64 + dc * 4;
#pragma unroll
  for (int i = 0; i < 4; ++i)
    Wt[(size_t)(nb + i) * 1024 + c] = f2bf(v[i]);
}

// ---------------- transpose V: QKV[:,2048+h*64+d] -> Vg[bh][d][t] ----------------
// grid (T/64, B*H), 256 thr. ~33MB traffic, bandwidth-bound (~6us).
__global__ __launch_bounds__(256)
void transpose_v(const u16* __restrict__ qkv, u16* __restrict__ Vg)
{
  const int T = 2048, C3 = 3072;
  const int tblk = blockIdx.x;    // 0..31
  const int bh = blockIdx.y;      // 0..63
  const int b = bh >> 4, h = bh & 15;
  __shared__ u16 tile[64][72];    // padded; aligned for b128 writes
  const int tid = threadIdx.x;
#pragma unroll
  for (int it = 0; it < 2; ++it) {
    int idx = it * 256 + tid;
    int t = idx >> 3, dc = idx & 7;
    short8 v = *reinterpret_cast<const short8*>(
        &qkv[(size_t)(b * T + tblk * 64 + t) * C3 + 2048 + h * 64 + dc * 8]);
    *reinterpret_cast<short8*>(&tile[t][dc * 8]) = v;
  }
  __syncthreads();
#pragma unroll
  for (int it = 0; it < 2; ++it) {
    int idx = it * 256 + tid;
    int d = idx >> 3, tb = idx & 7;
    short8 v;
#pragma unroll
    for (int i = 0; i < 8; ++i) v[i] = (short)tile[tb * 8 + i][d];
    *reinterpret_cast<short8*>(&Vg[((size_t)bh * 64 + d) * T + (size_t)tblk * 64 + tb * 8]) = v;
  }
}

// ---------------- GEMM: C[M,N] = A[M,K] * Bt[N,K]^T (+bias), bf16 in, fp32 acc ----------------
// 128x128 tile, 4 waves of 64x64, BK=32, global_load_lds staging (m97 structure)
template<bool BIAS, bool BF16_OUT>
__global__ __launch_bounds__(256)
void gemm_bt(const u16* __restrict__ A, const u16* __restrict__ Bt,
             const float* __restrict__ bias, void* __restrict__ Cout,
             int M, int N, int K)
{
  __shared__ u16 As[128 * 32];
  __shared__ u16 Bs[128 * 32];
  const int tid  = threadIdx.x;
  const int wave = tid >> 6, lane = tid & 63;
  const int l15 = lane & 15, l4 = lane >> 4;
  const int row0 = blockIdx.x * 128, col0 = blockIdx.y * 128;
  const int wr = (wave >> 1) * 64, wc = (wave & 1) * 64;

  f32x4 acc[4][4] = {};

  const int i0 = tid, i1 = tid + 256;
  const int ar0 = i0 >> 2, ac0 = (i0 & 3) * 8;
  const int ar1 = i1 >> 2, ac1 = (i1 & 3) * 8;

  for (int k0 = 0; k0 < K; k0 += 32) {
    __builtin_amdgcn_global_load_lds(
      (const __attribute__((address_space(1))) void*)(A + (size_t)(row0 + ar0) * K + k0 + ac0),
      (__attribute__((address_space(3))) void*)(As + wave * 512), 16, 0, 0);
    __builtin_amdgcn_global_load_lds(
      (const __attribute__((address_space(1))) void*)(A + (size_t)(row0 + ar1) * K + k0 + ac1),
      (__attribute__((address_space(3))) void*)(As + 2048 + wave * 512), 16, 0, 0);
    __builtin_amdgcn_global_load_lds(
      (const __attribute__((address_space(1))) void*)(Bt + (size_t)(col0 + ar0) * K + k0 + ac0),
      (__attribute__((address_space(3))) void*)(Bs + wave * 512), 16, 0, 0);
    __builtin_amdgcn_global_load_lds(
      (const __attribute__((address_space(1))) void*)(Bt + (size_t)(col0 + ar1) * K + k0 + ac1),
      (__attribute__((address_space(3))) void*)(Bs + 2048 + wave * 512), 16, 0, 0);
    __syncthreads();

    short8 af[4], bfr[4];
#pragma unroll
    for (int m = 0; m < 4; ++m)
      af[m] = *reinterpret_cast<const short8*>(&As[(wr + m * 16 + l15) * 32 + l4 * 8]);
#pragma unroll
    for (int n = 0; n < 4; ++n)
      bfr[n] = *reinterpret_cast<const short8*>(&Bs[(wc + n * 16 + l15) * 32 + l4 * 8]);
#pragma unroll
    for (int m = 0; m < 4; ++m)
#pragma unroll
      for (int n = 0; n < 4; ++n)
        acc[m][n] = __builtin_amdgcn_mfma_f32_16x16x32_bf16(af[m], bfr[n], acc[m][n], 0, 0, 0);
    __syncthreads();
  }

  u16* Cb = (u16*)Cout;
  float* Cf = (float*)Cout;
#pragma unroll
  for (int n = 0; n < 4; ++n) {
    const int c = col0 + wc + n * 16 + l15;
    const float bv = BIAS ? bias[c] : 0.0f;
#pragma unroll
    for (int m = 0; m < 4; ++m) {
      const int r0 = row0 + wr + m * 16 + l4 * 4;
#pragma unroll
      for (int r = 0; r < 4; ++r) {
        float v = acc[m][n][r] + bv;
        if (BF16_OUT) Cb[(size_t)(r0 + r) * N + c] = f2bf(v);
        else          Cf[(size_t)(r0 + r) * N + c] = v;
      }
    }
  }
}

// ---------------- flash attention ----------------
// QKV layout: [B*T][3072] bf16 (q at h*64, k at 1024+h*64); V^T from Vg[bh][d][t].
// 1D grid 2048 = (bh 0..63) x (qb 0..31), longest-first: qb = 31 - (bid&31).
// 256 thr = 4 waves, wave handles 16 queries; KV blocks of 64, causal skip kvb<=qb.
__global__ __launch_bounds__(256)
void attn_kernel(const u16* __restrict__ qkv, const u16* __restrict__ Vg, u16* __restrict__ att)
{
  const int T = 2048, C3 = 3072;
  const int bid = blockIdx.x;
  const int qb = 31 - (bid & 31);     // longest-first
  const int bh = bid >> 5;
  const int b = bh >> 4, h = bh & 15;
  const int tid = threadIdx.x, wave = tid >> 6, lane = tid & 63;
  const int l15 = lane & 15, l4 = lane >> 4;

  __shared__ u16 Ks[64][72];      // K tile [s][d], padded
  __shared__ u16 Vt[64][72];      // V^T tile [d][s], padded (vectorized writes now)
  __shared__ u16 Ps[4][16][72];   // per-wave P tile [t][s] (no cross-wave use -> no barrier)

  const size_t base = (size_t)b * T * C3 + (size_t)h * 64;
  const u16* qp = qkv + base;
  const u16* kp = qkv + base + 1024;
  const u16* vtp = Vg + (size_t)bh * 64 * T;

  // Q fragments (A-layout: row=l&15, k=(l>>4)*8+i), prescaled by 1/32 (exact pow2)
  const int tq = qb * 64 + wave * 16 + l15;
  short8 qf[2];
#pragma unroll
  for (int kk = 0; kk < 2; ++kk) {
    short8 v = *reinterpret_cast<const short8*>(&qp[(size_t)tq * C3 + kk * 32 + l4 * 8]);
#pragma unroll
    for (int i = 0; i < 8; ++i) {
      u16 raw = (u16)v[i];
      v[i] = (short)f2bf(bf2f(raw) * 0.03125f);
    }
    qf[kk] = v;
  }

  f32x4 o[4] = {};
  float mrun[4] = {-1e30f, -1e30f, -1e30f, -1e30f};
  float lrun[4] = {};

  for (int kvb = 0; kvb <= qb; ++kvb) {
    __syncthreads();   // prev iteration's MFMA reads of Ks/Vt done before restage
    // stage K tile [s][d] and V^T tile [d][s] — both fully vectorized b128 writes
#pragma unroll
    for (int it = 0; it < 2; ++it) {
      const int idx = it * 256 + tid;
      const int row = idx >> 3, cc = idx & 7;
      short8 kv = *reinterpret_cast<const short8*>(&kp[(size_t)(kvb * 64 + row) * C3 + cc * 8]);
      *reinterpret_cast<short8*>(&Ks[row][cc * 8]) = kv;
      short8 vv = *reinterpret_cast<const short8*>(&vtp[(size_t)row * T + kvb * 64 + cc * 8]);
      *reinterpret_cast<short8*>(&Vt[row][cc * 8]) = vv;
    }
    __syncthreads();

    // S = (Q*scale) K^T   [16 queries x 64 keys per wave]
    f32x4 s[4] = {};
#pragma unroll
    for (int n = 0; n < 4; ++n)
#pragma unroll
      for (int kk = 0; kk < 2; ++kk) {
        short8 b8 = *reinterpret_cast<const short8*>(&Ks[n * 16 + l15][kk * 32 + l4 * 8]);
        s[n] = __builtin_amdgcn_mfma_f32_16x16x32_bf16(qf[kk], b8, s[n], 0, 0, 0);
      }

    // causal mask (diagonal block only)
    if (kvb == qb) {
#pragma unroll
      for (int n = 0; n < 4; ++n)
#pragma unroll
        for (int r = 0; r < 4; ++r) {
          int sk = kvb * 64 + n * 16 + l15;
          int tr = qb * 64 + wave * 16 + l4 * 4 + r;
          if (sk > tr) s[n][r] = -1e30f;
        }
    }

    // row max over 4 n-blocks + 16 lanes
    float mb[4];
#pragma unroll
    for (int r = 0; r < 4; ++r)
      mb[r] = fmaxf(fmaxf(s[0][r], s[1][r]), fmaxf(s[2][r], s[3][r]));
#pragma unroll
    for (int xm = 1; xm <= 8; xm <<= 1)
#pragma unroll
      for (int r = 0; r < 4; ++r)
        mb[r] = fmaxf(mb[r], __shfl_xor(mb[r], xm));

    float alpha[4];
#pragma unroll
    for (int r = 0; r < 4; ++r) {
      float mn = fmaxf(mrun[r], mb[r]);
      alpha[r] = __expf(mrun[r] - mn);
      mrun[r] = mn;
    }

    // p = exp(s - m), row sums, stage P (bf16) to per-wave LDS slice
    float rs[4] = {};
#pragma unroll
    for (int n = 0; n < 4; ++n)
#pragma unroll
      for (int r = 0; r < 4; ++r) {
        float p = __expf(s[n][r] - mrun[r]);
        rs[r] += p;
        Ps[wave][l4 * 4 + r][n * 16 + l15] = f2bf(p);
      }
#pragma unroll
    for (int xm = 1; xm <= 8; xm <<= 1)
#pragma unroll
      for (int r = 0; r < 4; ++r)
        rs[r] += __shfl_xor(rs[r], xm);
#pragma unroll
    for (int r = 0; r < 4; ++r)
      lrun[r] = lrun[r] * alpha[r] + rs[r];
#pragma unroll
    for (int db = 0; db < 4; ++db)
#pragma unroll
      for (int r = 0; r < 4; ++r)
        o[db][r] *= alpha[r];

    // NO barrier here: Ps is per-wave (compiler inserts lgkmcnt for the
    // same-wave write->read dep); Vt was ordered by the post-stage barrier.

    // O += P V
#pragma unroll
    for (int kk = 0; kk < 2; ++kk) {
      short8 a8 = *reinterpret_cast<const short8*>(&Ps[wave][l15][kk * 32 + l4 * 8]);
#pragma unroll
      for (int db = 0; db < 4; ++db) {
        short8 b8 = *reinterpret_cast<const short8*>(&Vt[db * 16 + l15][kk * 32 + l4 * 8]);
        o[db] = __builtin_amdgcn_mfma_f32_16x16x32_bf16(a8, b8, o[db], 0, 0, 0);
      }
    }
  }

  // normalize + write att[b*T+t][h*64+d] (concat-head layout)
#pragma unroll
  for (int db = 0; db < 4; ++db)
#pragma unroll
    for (int r = 0; r < 4; ++r) {
      int t = qb * 64 + wave * 16 + l4 * 4 + r;
      float val = o[db][r] / lrun[r];
      att[(size_t)(b * T + t) * 1024 + h * 64 + db * 16 + l15] = f2bf(val);
    }
}

// ---------------- launch ----------------
extern "C" void kernel_launch(void* const* d_in, const int* in_sizes, int n_in,
                              void* d_out, int out_size, void* d_ws, size_t ws_size,
                              hipStream_t stream)
{
  const float* x  = (const float*)d_in[0];
  const float* wq = (const float*)d_in[1];
  const float* wk = (const float*)d_in[2];
  const float* wv = (const float*)d_in[3];
  const float* wp = (const float*)d_in[4];
  const float* bp = (const float*)d_in[5];
  float* out = (float*)d_out;

  u16* xb  = (u16*)d_ws;                       // 8192*1024 (dead after QKV gemm)
  u16* Wt  = xb  + (size_t)8192 * 1024;        // 3072*1024
  u16* wpb = Wt  + (size_t)3072 * 1024;        // 1024*1024
  u16* QKV = wpb + (size_t)1024 * 1024;        // 8192*3072
  u16* att = QKV + (size_t)8192 * 3072;        // 8192*1024
  u16* Vg  = xb;                               // alias: V^T [64 bh][64 d][2048 t]
  // total ws: 46.1M u16 = 92.3 MB

  cvt_f32_bf16<<<8192, 256, 0, stream>>>(x, xb);
  cvt_f32_bf16<<<1024, 256, 0, stream>>>(wp, wpb);
  repack_w<<<3072, 256, 0, stream>>>(wq, wk, wv, Wt);
  gemm_bt<false, true><<<dim3(64, 24), 256, 0, stream>>>(xb, Wt, nullptr, QKV, 8192, 3072, 1024);
  transpose_v<<<dim3(32, 64), 256, 0, stream>>>(QKV, Vg);
  attn_kernel<<<2048, 256, 0, stream>>>(QKV, Vg, att);
  gemm_bt<true, false><<<dim3(64, 8), 256, 0, stream>>>(att, wpb, bp, out, 8192, 1024, 1024);
}

// Round 5
// 414.591 us; speedup vs baseline: 1.2988x; 1.0644x over previous
//
#include <hip/hip_runtime.h>

typedef unsigned short u16;
typedef __attribute__((ext_vector_type(8))) short short8;
typedef __attribute__((ext_vector_type(4))) float f32x4;

__device__ __forceinline__ float bf2f(u16 v) {
  union { unsigned int u; float f; } c; c.u = ((unsigned int)v) << 16; return c.f;
}
__device__ __forceinline__ u16 f2bf(float f) {
  union { float f; unsigned int u; } c; c.f = f;
  unsigned int u = c.u;
  return (u16)((u + 0x7fffu + ((u >> 16) & 1u)) >> 16);
}

// ---------------- prep: fp32 -> bf16 elementwise (n divisible by 1024) ----------------
__global__ __launch_bounds__(256) void cvt_f32_bf16(const float* __restrict__ in, u16* __restrict__ out) {
  size_t i = ((size_t)blockIdx.x * 256 + threadIdx.x) * 4;
  f32x4 v = *reinterpret_cast<const f32x4*>(&in[i]);
  unsigned int lo = (unsigned int)f2bf(v[0]) | ((unsigned int)f2bf(v[1]) << 16);
  unsigned int hi = (unsigned int)f2bf(v[2]) | ((unsigned int)f2bf(v[3]) << 16);
  unsigned long long p = ((unsigned long long)hi << 32) | lo;
  *reinterpret_cast<unsigned long long*>(&out[i]) = p;
}

// ---------------- prep: wq/wk/wv [H=16][C=1024][D=64] fp32 -> Wt[n=3072][c=1024] bf16 (B^T) ----
__global__ __launch_bounds__(256) void repack_w(const float* __restrict__ wq, const float* __restrict__ wk,
                                                const float* __restrict__ wv, u16* __restrict__ Wt) {
  int tid = blockIdx.x * 256 + threadIdx.x;   // 786432 total
  int dc = tid & 15;            // d-chunk of 4
  int c  = (tid >> 4) & 1023;
  int h  = (tid >> 14) & 15;
  int which = tid >> 18;        // 0..2
  const float* src = which == 0 ? wq : (which == 1 ? wk : wv);
  f32x4 v = *reinterpret_cast<const f32x4*>(&src[(size_t)h * 65536 + (size_t)c * 64 + dc * 4]);
  int nb = which * 1024 + h * 64 + dc * 4;
#pragma unroll
  for (int i = 0; i < 4; ++i)
    Wt[(size_t)(nb + i) * 1024 + c] = f2bf(v[i]);
}

// ---------------- transpose V: QKV[:,2048+h*64+d] -> Vg[bh][d][t] ----------------
__global__ __launch_bounds__(256)
void transpose_v(const u16* __restrict__ qkv, u16* __restrict__ Vg)
{
  const int T = 2048, C3 = 3072;
  const int tblk = blockIdx.x;    // 0..31
  const int bh = blockIdx.y;      // 0..63
  const int b = bh >> 4, h = bh & 15;
  __shared__ u16 tile[64][72];    // padded; aligned for b128 writes
  const int tid = threadIdx.x;
#pragma unroll
  for (int it = 0; it < 2; ++it) {
    int idx = it * 256 + tid;
    int t = idx >> 3, dc = idx & 7;
    short8 v = *reinterpret_cast<const short8*>(
        &qkv[(size_t)(b * T + tblk * 64 + t) * C3 + 2048 + h * 64 + dc * 8]);
    *reinterpret_cast<short8*>(&tile[t][dc * 8]) = v;
  }
  __syncthreads();
#pragma unroll
  for (int it = 0; it < 2; ++it) {
    int idx = it * 256 + tid;
    int d = idx >> 3, tb = idx & 7;
    short8 v;
#pragma unroll
    for (int i = 0; i < 8; ++i) v[i] = (short)tile[tb * 8 + i][d];
    *reinterpret_cast<short8*>(&Vg[((size_t)bh * 64 + d) * T + (size_t)tblk * 64 + tb * 8]) = v;
  }
}

// ---------------- GEMM: C[M,N] = A[M,K] * Bt[N,K]^T (+bias), bf16 in, fp32 acc ----------------
// 128x128 tile, 4 waves of 64x64, BK=32, global_load_lds staging (m97 structure)
template<bool BIAS, bool BF16_OUT>
__global__ __launch_bounds__(256)
void gemm_bt(const u16* __restrict__ A, const u16* __restrict__ Bt,
             const float* __restrict__ bias, void* __restrict__ Cout,
             int M, int N, int K)
{
  __shared__ u16 As[128 * 32];
  __shared__ u16 Bs[128 * 32];
  const int tid  = threadIdx.x;
  const int wave = tid >> 6, lane = tid & 63;
  const int l15 = lane & 15, l4 = lane >> 4;
  const int row0 = blockIdx.x * 128, col0 = blockIdx.y * 128;
  const int wr = (wave >> 1) * 64, wc = (wave & 1) * 64;

  f32x4 acc[4][4] = {};

  const int i0 = tid, i1 = tid + 256;
  const int ar0 = i0 >> 2, ac0 = (i0 & 3) * 8;
  const int ar1 = i1 >> 2, ac1 = (i1 & 3) * 8;

  for (int k0 = 0; k0 < K; k0 += 32) {
    __builtin_amdgcn_global_load_lds(
      (const __attribute__((address_space(1))) void*)(A + (size_t)(row0 + ar0) * K + k0 + ac0),
      (__attribute__((address_space(3))) void*)(As + wave * 512), 16, 0, 0);
    __builtin_amdgcn_global_load_lds(
      (const __attribute__((address_space(1))) void*)(A + (size_t)(row0 + ar1) * K + k0 + ac1),
      (__attribute__((address_space(3))) void*)(As + 2048 + wave * 512), 16, 0, 0);
    __builtin_amdgcn_global_load_lds(
      (const __attribute__((address_space(1))) void*)(Bt + (size_t)(col0 + ar0) * K + k0 + ac0),
      (__attribute__((address_space(3))) void*)(Bs + wave * 512), 16, 0, 0);
    __builtin_amdgcn_global_load_lds(
      (const __attribute__((address_space(1))) void*)(Bt + (size_t)(col0 + ar1) * K + k0 + ac1),
      (__attribute__((address_space(3))) void*)(Bs + 2048 + wave * 512), 16, 0, 0);
    __syncthreads();

    short8 af[4], bfr[4];
#pragma unroll
    for (int m = 0; m < 4; ++m)
      af[m] = *reinterpret_cast<const short8*>(&As[(wr + m * 16 + l15) * 32 + l4 * 8]);
#pragma unroll
    for (int n = 0; n < 4; ++n)
      bfr[n] = *reinterpret_cast<const short8*>(&Bs[(wc + n * 16 + l15) * 32 + l4 * 8]);
#pragma unroll
    for (int m = 0; m < 4; ++m)
#pragma unroll
      for (int n = 0; n < 4; ++n)
        acc[m][n] = __builtin_amdgcn_mfma_f32_16x16x32_bf16(af[m], bfr[n], acc[m][n], 0, 0, 0);
    __syncthreads();
  }

  u16* Cb = (u16*)Cout;
  float* Cf = (float*)Cout;
#pragma unroll
  for (int n = 0; n < 4; ++n) {
    const int c = col0 + wc + n * 16 + l15;
    const float bv = BIAS ? bias[c] : 0.0f;
#pragma unroll
    for (int m = 0; m < 4; ++m) {
      const int r0 = row0 + wr + m * 16 + l4 * 4;
#pragma unroll
      for (int r = 0; r < 4; ++r) {
        float v = acc[m][n][r] + bv;
        if (BF16_OUT) Cb[(size_t)(r0 + r) * N + c] = f2bf(v);
        else          Cf[(size_t)(r0 + r) * N + c] = v;
      }
    }
  }
}

// ---------------- flash attention ----------------
// QKV layout: [B*T][3072] bf16 (q at h*64, k at 1024+h*64); V^T from Vg[bh][d][t].
// 512 thr = 8 waves; QBLK=128 (wave w owns rows w*16..w*16+15); KV tiles of 64.
// Grid 1024 = (bh 0..63) x (qb 0..15), longest-first: qb = 15 - (bid&15).
// Register prefetch: next tile's K/V loads issued during compute (T14 async-STAGE).
__global__ __launch_bounds__(512, 4)
void attn_kernel(const u16* __restrict__ qkv, const u16* __restrict__ Vg, u16* __restrict__ att)
{
  const int T = 2048, C3 = 3072;
  const int bid = blockIdx.x;
  const int qb = 15 - (bid & 15);     // longest-first
  const int bh = bid >> 4;
  const int b = bh >> 4, h = bh & 15;
  const int tid = threadIdx.x, wave = tid >> 6, lane = tid & 63;
  const int l15 = lane & 15, l4 = lane >> 4;

  __shared__ u16 Ks[64][72];      // K tile [s][d], padded
  __shared__ u16 Vt[64][72];      // V^T tile [d][s], padded
  __shared__ u16 Ps[8][16][72];   // per-wave P tile [t][s] (no cross-wave use -> no barrier)

  const size_t base = (size_t)b * T * C3 + (size_t)h * 64;
  const u16* qp = qkv + base;
  const u16* kp = qkv + base + 1024;
  const u16* vtp = Vg + (size_t)bh * 64 * T;

  // Q fragments (A-layout: row=l&15, k=(l>>4)*8+i), prescaled by log2(e)/32
  // so scores live in the exp2 domain (v_exp_f32 is native 2^x).
  const int tq = qb * 128 + wave * 16 + l15;
  short8 qf[2];
#pragma unroll
  for (int kk = 0; kk < 2; ++kk) {
    short8 v = *reinterpret_cast<const short8*>(&qp[(size_t)tq * C3 + kk * 32 + l4 * 8]);
#pragma unroll
    for (int i = 0; i < 8; ++i) {
      u16 raw = (u16)v[i];
      v[i] = (short)f2bf(bf2f(raw) * 0.04508422f);   // (1/32)*log2(e)
    }
    qf[kk] = v;
  }

  // staging: 512 threads -> one short8 of K and one of V^T per thread per tile
  const int srow = tid >> 3, scc = tid & 7;
  const int kv_last = 2 * qb + 1;

  short8 kreg = *reinterpret_cast<const short8*>(&kp[(size_t)srow * C3 + scc * 8]);
  short8 vreg = *reinterpret_cast<const short8*>(&vtp[(size_t)srow * T + scc * 8]);

  f32x4 o[4] = {};
  float mrun[4] = {-1e30f, -1e30f, -1e30f, -1e30f};
  float lrun[4] = {};

  for (int kvb = 0; kvb <= kv_last; ++kvb) {
    __syncthreads();   // prev iteration's MFMA reads of Ks/Vt done before overwrite
    *reinterpret_cast<short8*>(&Ks[srow][scc * 8]) = kreg;   // vmcnt wait auto-inserted
    *reinterpret_cast<short8*>(&Vt[srow][scc * 8]) = vreg;
    __syncthreads();

    // issue NEXT tile's loads now — latency hides under QK/softmax/PV
    if (kvb < kv_last) {
      kreg = *reinterpret_cast<const short8*>(&kp[(size_t)((kvb + 1) * 64 + srow) * C3 + scc * 8]);
      vreg = *reinterpret_cast<const short8*>(&vtp[(size_t)srow * T + (kvb + 1) * 64 + scc * 8]);
    }

    // S = (Q*scale*log2e) K^T   [16 queries x 64 keys per wave]
    f32x4 s[4] = {};
#pragma unroll
    for (int n = 0; n < 4; ++n)
#pragma unroll
      for (int kk = 0; kk < 2; ++kk) {
        short8 b8 = *reinterpret_cast<const short8*>(&Ks[n * 16 + l15][kk * 32 + l4 * 8]);
        s[n] = __builtin_amdgcn_mfma_f32_16x16x32_bf16(qf[kk], b8, s[n], 0, 0, 0);
      }

    // causal mask (only the last two KV tiles can straddle the diagonal)
    if (kvb >= 2 * qb) {
#pragma unroll
      for (int n = 0; n < 4; ++n)
#pragma unroll
        for (int r = 0; r < 4; ++r) {
          int sk = kvb * 64 + n * 16 + l15;
          int tr = qb * 128 + wave * 16 + l4 * 4 + r;
          if (sk > tr) s[n][r] = -1e30f;
        }
    }

    // row max over 4 n-blocks + 16 lanes
    float mb[4];
#pragma unroll
    for (int r = 0; r < 4; ++r)
      mb[r] = fmaxf(fmaxf(s[0][r], s[1][r]), fmaxf(s[2][r], s[3][r]));
#pragma unroll
    for (int xm = 1; xm <= 8; xm <<= 1)
#pragma unroll
      for (int r = 0; r < 4; ++r)
        mb[r] = fmaxf(mb[r], __shfl_xor(mb[r], xm));

    float alpha[4];
#pragma unroll
    for (int r = 0; r < 4; ++r) {
      float mn = fmaxf(mrun[r], mb[r]);
      alpha[r] = __builtin_exp2f(mrun[r] - mn);
      mrun[r] = mn;
    }

    // p = 2^(s - m), row sums, stage P (bf16) to per-wave LDS slice
    float rs[4] = {};
#pragma unroll
    for (int n = 0; n < 4; ++n)
#pragma unroll
      for (int r = 0; r < 4; ++r) {
        float p = __builtin_exp2f(s[n][r] - mrun[r]);
        rs[r] += p;
        Ps[wave][l4 * 4 + r][n * 16 + l15] = f2bf(p);
      }
#pragma unroll
    for (int xm = 1; xm <= 8; xm <<= 1)
#pragma unroll
      for (int r = 0; r < 4; ++r)
        rs[r] += __shfl_xor(rs[r], xm);
#pragma unroll
    for (int r = 0; r < 4; ++r)
      lrun[r] = lrun[r] * alpha[r] + rs[r];
#pragma unroll
    for (int db = 0; db < 4; ++db)
#pragma unroll
      for (int r = 0; r < 4; ++r)
        o[db][r] *= alpha[r];

    // NO barrier: Ps is per-wave (same-wave write->read ordered by lgkmcnt).

    // O += P V
#pragma unroll
    for (int kk = 0; kk < 2; ++kk) {
      short8 a8 = *reinterpret_cast<const short8*>(&Ps[wave][l15][kk * 32 + l4 * 8]);
#pragma unroll
      for (int db = 0; db < 4; ++db) {
        short8 b8 = *reinterpret_cast<const short8*>(&Vt[db * 16 + l15][kk * 32 + l4 * 8]);
        o[db] = __builtin_amdgcn_mfma_f32_16x16x32_bf16(a8, b8, o[db], 0, 0, 0);
      }
    }
  }

  // normalize + write att[b*T+t][h*64+d] (concat-head layout)
#pragma unroll
  for (int db = 0; db < 4; ++db)
#pragma unroll
    for (int r = 0; r < 4; ++r) {
      int t = qb * 128 + wave * 16 + l4 * 4 + r;
      float val = o[db][r] / lrun[r];
      att[(size_t)(b * T + t) * 1024 + h * 64 + db * 16 + l15] = f2bf(val);
    }
}

// ---------------- launch ----------------
extern "C" void kernel_launch(void* const* d_in, const int* in_sizes, int n_in,
                              void* d_out, int out_size, void* d_ws, size_t ws_size,
                              hipStream_t stream)
{
  const float* x  = (const float*)d_in[0];
  const float* wq = (const float*)d_in[1];
  const float* wk = (const float*)d_in[2];
  const float* wv = (const float*)d_in[3];
  const float* wp = (const float*)d_in[4];
  const float* bp = (const float*)d_in[5];
  float* out = (float*)d_out;

  u16* xb  = (u16*)d_ws;                       // 8192*1024 (dead after QKV gemm)
  u16* Wt  = xb  + (size_t)8192 * 1024;        // 3072*1024
  u16* wpb = Wt  + (size_t)3072 * 1024;        // 1024*1024
  u16* QKV = wpb + (size_t)1024 * 1024;        // 8192*3072
  u16* att = QKV + (size_t)8192 * 3072;        // 8192*1024
  u16* Vg  = xb;                               // alias: V^T [64 bh][64 d][2048 t]
  // total ws: 46.1M u16 = 92.3 MB

  cvt_f32_bf16<<<8192, 256, 0, stream>>>(x, xb);
  cvt_f32_bf16<<<1024, 256, 0, stream>>>(wp, wpb);
  repack_w<<<3072, 256, 0, stream>>>(wq, wk, wv, Wt);
  gemm_bt<false, true><<<dim3(64, 24), 256, 0, stream>>>(xb, Wt, nullptr, QKV, 8192, 3072, 1024);
  transpose_v<<<dim3(32, 64), 256, 0, stream>>>(QKV, Vg);
  attn_kernel<<<1024, 512, 0, stream>>>(QKV, Vg, att);
  gemm_bt<true, false><<<dim3(64, 8), 256, 0, stream>>>(att, wpb, bp, out, 8192, 1024, 1024);
}

// Round 13
// 344.332 us; speedup vs baseline: 1.5638x; 1.2040x over previous
//
#include <hip/hip_runtime.h>

typedef unsigned short u16;
typedef __attribute__((ext_vector_type(8))) short short8;
typedef __attribute__((ext_vector_type(4))) float f32x4;
typedef __attribute__((ext_vector_type(16))) float f32x16;

__device__ __forceinline__ float bf2f(u16 v) {
  union { unsigned int u; float f; } c; c.u = ((unsigned int)v) << 16; return c.f;
}
__device__ __forceinline__ u16 f2bf(float f) {
  union { float f; unsigned int u; } c; c.f = f;
  unsigned int u = c.u;
  return (u16)((u + 0x7fffu + ((u >> 16) & 1u)) >> 16);
}
// v_cvt_pk_bf16_f32: dst.lo=bf16(a), dst.hi=bf16(b)  (verified recipe, m214v22/m240)
__device__ __forceinline__ unsigned cvtpk(float a, float b) {
  unsigned r; asm("v_cvt_pk_bf16_f32 %0, %1, %2" : "=v"(r) : "v"(a), "v"(b)); return r;
}

// ---------------- prep: fp32 -> bf16 elementwise (n divisible by 1024) ----------------
__global__ __launch_bounds__(256) void cvt_f32_bf16(const float* __restrict__ in, u16* __restrict__ out) {
  size_t i = ((size_t)blockIdx.x * 256 + threadIdx.x) * 4;
  f32x4 v = *reinterpret_cast<const f32x4*>(&in[i]);
  unsigned int lo = (unsigned int)f2bf(v[0]) | ((unsigned int)f2bf(v[1]) << 16);
  unsigned int hi = (unsigned int)f2bf(v[2]) | ((unsigned int)f2bf(v[3]) << 16);
  unsigned long long p = ((unsigned long long)hi << 32) | lo;
  *reinterpret_cast<unsigned long long*>(&out[i]) = p;
}

// ---- prep: wq/wk/wv [H=16][C=1024][D=64] fp32 -> Wt[n=3072][c=1024] bf16 (B^T) ----
// Wq is pre-scaled by (1/32)*log2(e) so attention scores land in the exp2 domain.
__global__ __launch_bounds__(256) void repack_w(const float* __restrict__ wq, const float* __restrict__ wk,
                                                const float* __restrict__ wv, u16* __restrict__ Wt) {
  int tid = blockIdx.x * 256 + threadIdx.x;   // 786432 total
  int dc = tid & 15;
  int c  = (tid >> 4) & 1023;
  int h  = (tid >> 14) & 15;
  int which = tid >> 18;        // 0..2
  const float* src = which == 0 ? wq : (which == 1 ? wk : wv);
  const float scl = (which == 0) ? 0.04508422f : 1.0f;   // log2(e)/32
  f32x4 v = *reinterpret_cast<const f32x4*>(&src[(size_t)h * 65536 + (size_t)c * 64 + dc * 4]);
  int nb = which * 1024 + h * 64 + dc * 4;
#pragma unroll
  for (int i = 0; i < 4; ++i)
    Wt[(size_t)(nb + i) * 1024 + c] = f2bf(v[i] * scl);
}

// ---------------- transpose V: QKV[:,2048+h*64+d] -> Vg[bh][d][t] ----------------
__global__ __launch_bounds__(256)
void transpose_v(const u16* __restrict__ qkv, u16* __restrict__ Vg)
{
  const int T = 2048, C3 = 3072;
  const int tblk = blockIdx.x;    // 0..31
  const int bh = blockIdx.y;      // 0..63
  const int b = bh >> 4, h = bh & 15;
  __shared__ u16 tile[64][72];
  const int tid = threadIdx.x;
#pragma unroll
  for (int it = 0; it < 2; ++it) {
    int idx = it * 256 + tid;
    int t = idx >> 3, dc = idx & 7;
    short8 v = *reinterpret_cast<const short8*>(
        &qkv[(size_t)(b * T + tblk * 64 + t) * C3 + 2048 + h * 64 + dc * 8]);
    *reinterpret_cast<short8*>(&tile[t][dc * 8]) = v;
  }
  __syncthreads();
#pragma unroll
  for (int it = 0; it < 2; ++it) {
    int idx = it * 256 + tid;
    int d = idx >> 3, tb = idx & 7;
    short8 v;
#pragma unroll
    for (int i = 0; i < 8; ++i) v[i] = (short)tile[tb * 8 + i][d];
    *reinterpret_cast<short8*>(&Vg[((size_t)bh * 64 + d) * T + (size_t)tblk * 64 + tb * 8]) = v;
  }
}

// ---------------- GEMM: C[M,N] = A[M,K] * Bt[N,K]^T (+bias), bf16 in, fp32 acc ----------------
template<bool BIAS, bool BF16_OUT>
__global__ __launch_bounds__(256)
void gemm_bt(const u16* __restrict__ A, const u16* __restrict__ Bt,
             const float* __restrict__ bias, void* __restrict__ Cout,
             int M, int N, int K)
{
  __shared__ u16 As[128 * 32];
  __shared__ u16 Bs[128 * 32];
  const int tid  = threadIdx.x;
  const int wave = tid >> 6, lane = tid & 63;
  const int l15 = lane & 15, l4 = lane >> 4;
  const int row0 = blockIdx.x * 128, col0 = blockIdx.y * 128;
  const int wr = (wave >> 1) * 64, wc = (wave & 1) * 64;

  f32x4 acc[4][4] = {};

  const int i0 = tid, i1 = tid + 256;
  const int ar0 = i0 >> 2, ac0 = (i0 & 3) * 8;
  const int ar1 = i1 >> 2, ac1 = (i1 & 3) * 8;

  for (int k0 = 0; k0 < K; k0 += 32) {
    __builtin_amdgcn_global_load_lds(
      (const __attribute__((address_space(1))) void*)(A + (size_t)(row0 + ar0) * K + k0 + ac0),
      (__attribute__((address_space(3))) void*)(As + wave * 512), 16, 0, 0);
    __builtin_amdgcn_global_load_lds(
      (const __attribute__((address_space(1))) void*)(A + (size_t)(row0 + ar1) * K + k0 + ac1),
      (__attribute__((address_space(3))) void*)(As + 2048 + wave * 512), 16, 0, 0);
    __builtin_amdgcn_global_load_lds(
      (const __attribute__((address_space(1))) void*)(Bt + (size_t)(col0 + ar0) * K + k0 + ac0),
      (__attribute__((address_space(3))) void*)(Bs + wave * 512), 16, 0, 0);
    __builtin_amdgcn_global_load_lds(
      (const __attribute__((address_space(1))) void*)(Bt + (size_t)(col0 + ar1) * K + k0 + ac1),
      (__attribute__((address_space(3))) void*)(Bs + 2048 + wave * 512), 16, 0, 0);
    __syncthreads();

    short8 af[4], bfr[4];
#pragma unroll
    for (int m = 0; m < 4; ++m)
      af[m] = *reinterpret_cast<const short8*>(&As[(wr + m * 16 + l15) * 32 + l4 * 8]);
#pragma unroll
    for (int n = 0; n < 4; ++n)
      bfr[n] = *reinterpret_cast<const short8*>(&Bs[(wc + n * 16 + l15) * 32 + l4 * 8]);
#pragma unroll
    for (int m = 0; m < 4; ++m)
#pragma unroll
      for (int n = 0; n < 4; ++n)
        acc[m][n] = __builtin_amdgcn_mfma_f32_16x16x32_bf16(af[m], bfr[n], acc[m][n], 0, 0, 0);
    __syncthreads();
  }

  u16* Cb = (u16*)Cout;
  float* Cf = (float*)Cout;
#pragma unroll
  for (int n = 0; n < 4; ++n) {
    const int c = col0 + wc + n * 16 + l15;
    const float bv = BIAS ? bias[c] : 0.0f;
#pragma unroll
    for (int m = 0; m < 4; ++m) {
      const int r0 = row0 + wr + m * 16 + l4 * 4;
#pragma unroll
      for (int r = 0; r < 4; ++r) {
        float v = acc[m][n][r] + bv;
        if (BF16_OUT) Cb[(size_t)(r0 + r) * N + c] = f2bf(v);
        else          Cf[(size_t)(r0 + r) * N + c] = v;
      }
    }
  }
}

// ---------------- flash attention, swapped-QK in-register softmax ----------------
// 256 thr = 4 waves; wave w owns 32 queries (QBLK=128); KV tiles of 64 (2 x 32 sub-tiles).
// S^T = mfma32x32(K, Q): lane holds 16 score regs for ONE query col (q = lane&31).
// ALL cross-half redistribution via __shfl_xor(.,32) (direction-unambiguous; the
// R8 failure's prime suspect was v_permlane32_swap operand-direction).
__global__ __launch_bounds__(256, 3)
void attn_kernel(const u16* __restrict__ qkv, const u16* __restrict__ Vg, u16* __restrict__ att)
{
  const int T = 2048, C3 = 3072;
  const int bid = blockIdx.x;
  const int qb = 15 - (bid & 15);     // longest-first
  const int bh = bid >> 4;
  const int b = bh >> 4, h = bh & 15;
  const int tid = threadIdx.x, w = tid >> 6, lane = tid & 63;
  const int l31 = lane & 31, hh = lane >> 5;

  __shared__ u16 sh[2][64][72];       // [0]=K [s][d], [1]=V^T [d][s]; reused by epilogue
  u16 (*Ks)[72] = sh[0];
  u16 (*Vt)[72] = sh[1];

  const size_t base = (size_t)b * T * C3 + (size_t)h * 64;
  const u16* qp  = qkv + base;            // pre-scaled by log2e/32 via repack_w
  const u16* kp  = qkv + base + 1024;
  const u16* vtp = Vg + (size_t)bh * 64 * T;

  // Q B-fragments: B[k=d][col=q], lane: col=l31, k=hh*8+i within d-tile j
  const int q = qb * 128 + w * 32 + l31;
  short8 qf[4];
#pragma unroll
  for (int j = 0; j < 4; ++j)
    qf[j] = *reinterpret_cast<const short8*>(&qp[(size_t)q * C3 + j * 16 + hh * 8]);

  // staging: thread -> row tid>>2, col chunk (tid&3)*16 (two short8 each for K and V^T)
  const int srow = tid >> 2, scc = (tid & 3) * 16;
  short8 kr0 = *reinterpret_cast<const short8*>(&kp[(size_t)srow * C3 + scc]);
  short8 kr1 = *reinterpret_cast<const short8*>(&kp[(size_t)srow * C3 + scc + 8]);
  short8 vr0 = *reinterpret_cast<const short8*>(&vtp[(size_t)srow * T + scc]);
  short8 vr1 = *reinterpret_cast<const short8*>(&vtp[(size_t)srow * T + scc + 8]);

  f32x16 o0 = {}, o1 = {};            // O^T accum: d-tiles 0 (d0..31) and 1 (d32..63)
  float mrun = -1e30f, lrun = 0.0f;

  const int kv_last = 2 * qb + 1;
  const int qmin_w = qb * 128 + w * 32, qmax_w = qmin_w + 31;

  for (int kvb = 0; kvb <= kv_last; ++kvb) {
    __syncthreads();                  // prev tile's readers done
    *reinterpret_cast<short8*>(&Ks[srow][scc])     = kr0;
    *reinterpret_cast<short8*>(&Ks[srow][scc + 8]) = kr1;
    *reinterpret_cast<short8*>(&Vt[srow][scc])     = vr0;
    *reinterpret_cast<short8*>(&Vt[srow][scc + 8]) = vr1;
    __syncthreads();                  // tile visible

    if (kvb < kv_last) {              // prefetch next tile (hides under compute)
      const u16* kn = kp + (size_t)((kvb + 1) * 64 + srow) * C3 + scc;
      kr0 = *reinterpret_cast<const short8*>(kn);
      kr1 = *reinterpret_cast<const short8*>(kn + 8);
      const u16* vn = vtp + (size_t)srow * T + (kvb + 1) * 64 + scc;
      vr0 = *reinterpret_cast<const short8*>(vn);
      vr1 = *reinterpret_cast<const short8*>(vn + 8);
    }

#pragma unroll
    for (int st = 0; st < 2; ++st) {
      const int sbase = kvb * 64 + st * 32;
      if (sbase > qmax_w) continue;   // wave-uniform causal skip

      // S^T = K x Q : D[s][q], lane: q=l31, s-slots (r&3)+8*(r>>2)+4*hh
      f32x16 sc = {};
#pragma unroll
      for (int j = 0; j < 4; ++j) {
        short8 ka = *reinterpret_cast<const short8*>(&Ks[st * 32 + l31][j * 16 + hh * 8]);
        sc = __builtin_amdgcn_mfma_f32_32x32x16_bf16(ka, qf[j], sc, 0, 0, 0);
      }

      if (sbase + 31 > qmin_w) {      // diagonal overlap -> causal mask
#pragma unroll
        for (int r = 0; r < 16; ++r) {
          int sg = sbase + (r & 3) + 8 * (r >> 2) + 4 * hh;
          if (sg > q) sc[r] = -1e30f;
        }
      }

      // column (per-query) max: in-lane tree over 16 slots + cross-half shfl
      float a0 = fmaxf(sc[0], sc[1]),  a1 = fmaxf(sc[2], sc[3]);
      float a2 = fmaxf(sc[4], sc[5]),  a3 = fmaxf(sc[6], sc[7]);
      float a4 = fmaxf(sc[8], sc[9]),  a5 = fmaxf(sc[10], sc[11]);
      float a6 = fmaxf(sc[12], sc[13]), a7 = fmaxf(sc[14], sc[15]);
      a0 = fmaxf(a0, a1); a2 = fmaxf(a2, a3); a4 = fmaxf(a4, a5); a6 = fmaxf(a6, a7);
      a0 = fmaxf(a0, a2); a4 = fmaxf(a4, a6);
      float mt = fmaxf(a0, a4);
      mt = fmaxf(mt, __shfl_xor(mt, 32));

      float mn = fmaxf(mrun, mt);
      float alpha = __builtin_exp2f(mrun - mn);
      mrun = mn;

      float p[16];
#pragma unroll
      for (int r = 0; r < 16; ++r) p[r] = __builtin_exp2f(sc[r] - mn);
      float s0 = (p[0] + p[1]) + (p[2] + p[3]);
      float s1 = (p[4] + p[5]) + (p[6] + p[7]);
      float s2 = (p[8] + p[9]) + (p[10] + p[11]);
      float s3 = (p[12] + p[13]) + (p[14] + p[15]);
      float rs = (s0 + s1) + (s2 + s3);
      rs += __shfl_xor(rs, 32);

      lrun = lrun * alpha + rs;
      o0 = o0 * alpha;
      o1 = o1 * alpha;

      // pack P^T into PV B-fragment dwords.
      // own slots (r=0..7):  c0={s 0+4hh,1+4hh} c1={2+4hh,3+4hh} c2={8+4hh,9+4hh} c3={10+4hh,11+4hh}
      // B-frag needs k = hh*8 + {0..7}:
      //   hh=0: {c0, c1, partner c0, partner c1}
      //   hh=1: {partner c2, partner c3, c2, c3}
      unsigned c0 = cvtpk(p[0], p[1]),   c1 = cvtpk(p[2], p[3]);
      unsigned c2 = cvtpk(p[4], p[5]),   c3 = cvtpk(p[6], p[7]);
      unsigned c4 = cvtpk(p[8], p[9]),   c5 = cvtpk(p[10], p[11]);
      unsigned c6 = cvtpk(p[12], p[13]), c7 = cvtpk(p[14], p[15]);
      unsigned x0 = __shfl_xor(c0, 32), x1 = __shfl_xor(c1, 32);
      unsigned x2 = __shfl_xor(c2, 32), x3 = __shfl_xor(c3, 32);
      unsigned x4 = __shfl_xor(c4, 32), x5 = __shfl_xor(c5, 32);
      unsigned x6 = __shfl_xor(c6, 32), x7 = __shfl_xor(c7, 32);
      union PU { unsigned u[4]; short8 s8; };
      PU pu0, pu1;
      pu0.u[0] = hh ? x2 : c0;  pu0.u[1] = hh ? x3 : c1;
      pu0.u[2] = hh ? c2 : x0;  pu0.u[3] = hh ? c3 : x1;
      pu1.u[0] = hh ? x6 : c4;  pu1.u[1] = hh ? x7 : c5;
      pu1.u[2] = hh ? c6 : x4;  pu1.u[3] = hh ? c7 : x5;

      // O^T += V^T x P^T
#pragma unroll
      for (int sm = 0; sm < 2; ++sm) {
        short8 pb = sm ? pu1.s8 : pu0.s8;
        short8 va0 = *reinterpret_cast<const short8*>(&Vt[l31][st * 32 + sm * 16 + hh * 8]);
        o0 = __builtin_amdgcn_mfma_f32_32x32x16_bf16(va0, pb, o0, 0, 0, 0);
        short8 va1 = *reinterpret_cast<const short8*>(&Vt[32 + l31][st * 32 + sm * 16 + hh * 8]);
        o1 = __builtin_amdgcn_mfma_f32_32x32x16_bf16(va1, pb, o1, 0, 0, 0);
      }
    }
  }

  // epilogue: normalize, LDS transpose (per-wave region), coalesced store
  __syncthreads();                    // all waves done reading Ks/Vt
  const float inv = 1.0f / lrun;
  u16* ep = (u16*)sh + w * 2304 + l31 * 72;   // [32 q][72] per wave
#pragma unroll
  for (int k = 0; k < 8; ++k) {
    const int d0 = ((k & 1) * 2) + ((k >> 1) * 8) + 4 * hh;
    *reinterpret_cast<unsigned*>(&ep[d0])      = cvtpk(o0[2 * k] * inv, o0[2 * k + 1] * inv);
    *reinterpret_cast<unsigned*>(&ep[32 + d0]) = cvtpk(o1[2 * k] * inv, o1[2 * k + 1] * inv);
  }
  __syncthreads();
  const int rr = lane >> 1, cc0 = (lane & 1) * 32;
  const u16* epw = (u16*)sh + w * 2304 + rr * 72 + cc0;
  u16* op = att + (size_t)(b * T + qb * 128 + w * 32 + rr) * 1024 + h * 64 + cc0;
#pragma unroll
  for (int c = 0; c < 4; ++c)
    *reinterpret_cast<short8*>(&op[c * 8]) = *reinterpret_cast<const short8*>(&epw[c * 8]);
}

// ---------------- launch ----------------
extern "C" void kernel_launch(void* const* d_in, const int* in_sizes, int n_in,
                              void* d_out, int out_size, void* d_ws, size_t ws_size,
                              hipStream_t stream)
{
  const float* x  = (const float*)d_in[0];
  const float* wq = (const float*)d_in[1];
  const float* wk = (const float*)d_in[2];
  const float* wv = (const float*)d_in[3];
  const float* wp = (const float*)d_in[4];
  const float* bp = (const float*)d_in[5];
  float* out = (float*)d_out;

  u16* xb  = (u16*)d_ws;                       // 8192*1024 (dead after QKV gemm)
  u16* Wt  = xb  + (size_t)8192 * 1024;        // 3072*1024
  u16* wpb = Wt  + (size_t)3072 * 1024;        // 1024*1024
  u16* QKV = wpb + (size_t)1024 * 1024;        // 8192*3072
  u16* att = QKV + (size_t)8192 * 3072;        // 8192*1024
  u16* Vg  = xb;                               // alias: V^T [64 bh][64 d][2048 t]
  // total ws: 46.1M u16 = 92.3 MB

  cvt_f32_bf16<<<8192, 256, 0, stream>>>(x, xb);
  cvt_f32_bf16<<<1024, 256, 0, stream>>>(wp, wpb);
  repack_w<<<3072, 256, 0, stream>>>(wq, wk, wv, Wt);
  gemm_bt<false, true><<<dim3(64, 24), 256, 0, stream>>>(xb, Wt, nullptr, QKV, 8192, 3072, 1024);
  transpose_v<<<dim3(32, 64), 256, 0, stream>>>(QKV, Vg);
  attn_kernel<<<1024, 256, 0, stream>>>(QKV, Vg, att);
  gemm_bt<true, false><<<dim3(64, 8), 256, 0, stream>>>(att, wpb, bp, out, 8192, 1024, 1024);
}

// Round 14
// 299.075 us; speedup vs baseline: 1.8005x; 1.1513x over previous
//
#include <hip/hip_runtime.h>

typedef unsigned short u16;
typedef __attribute__((ext_vector_type(8))) short short8;
typedef __attribute__((ext_vector_type(4))) float f32x4;
typedef __attribute__((ext_vector_type(16))) float f32x16;

__device__ __forceinline__ float bf2f(u16 v) {
  union { unsigned int u; float f; } c; c.u = ((unsigned int)v) << 16; return c.f;
}
__device__ __forceinline__ u16 f2bf(float f) {
  union { float f; unsigned int u; } c; c.f = f;
  unsigned int u = c.u;
  return (u16)((u + 0x7fffu + ((u >> 16) & 1u)) >> 16);
}
// v_cvt_pk_bf16_f32: dst.lo=bf16(a), dst.hi=bf16(b)  (verified recipe, m214v22/m240)
__device__ __forceinline__ unsigned cvtpk(float a, float b) {
  unsigned r; asm("v_cvt_pk_bf16_f32 %0, %1, %2" : "=v"(r) : "v"(a), "v"(b)); return r;
}

// ---------------- prep: fp32 -> bf16 elementwise (n divisible by 1024) ----------------
__global__ __launch_bounds__(256) void cvt_f32_bf16(const float* __restrict__ in, u16* __restrict__ out) {
  size_t i = ((size_t)blockIdx.x * 256 + threadIdx.x) * 4;
  f32x4 v = *reinterpret_cast<const f32x4*>(&in[i]);
  unsigned int lo = (unsigned int)f2bf(v[0]) | ((unsigned int)f2bf(v[1]) << 16);
  unsigned int hi = (unsigned int)f2bf(v[2]) | ((unsigned int)f2bf(v[3]) << 16);
  unsigned long long p = ((unsigned long long)hi << 32) | lo;
  *reinterpret_cast<unsigned long long*>(&out[i]) = p;
}

// ---- prep: wq/wk/wv [H=16][C=1024][D=64] fp32 -> Wt[n=3072][c=1024] bf16 (B^T) ----
// Wq is pre-scaled by (1/32)*log2(e) so attention scores land in the exp2 domain.
__global__ __launch_bounds__(256) void repack_w(const float* __restrict__ wq, const float* __restrict__ wk,
                                                const float* __restrict__ wv, u16* __restrict__ Wt) {
  int tid = blockIdx.x * 256 + threadIdx.x;   // 786432 total
  int dc = tid & 15;
  int c  = (tid >> 4) & 1023;
  int h  = (tid >> 14) & 15;
  int which = tid >> 18;        // 0..2
  const float* src = which == 0 ? wq : (which == 1 ? wk : wv);
  const float scl = (which == 0) ? 0.04508422f : 1.0f;   // log2(e)/32
  f32x4 v = *reinterpret_cast<const f32x4*>(&src[(size_t)h * 65536 + (size_t)c * 64 + dc * 4]);
  int nb = which * 1024 + h * 64 + dc * 4;
#pragma unroll
  for (int i = 0; i < 4; ++i)
    Wt[(size_t)(nb + i) * 1024 + c] = f2bf(v[i] * scl);
}

// ---------------- transpose V: QKV[:,2048+h*64+d] -> Vg[bh][d][t] ----------------
__global__ __launch_bounds__(256)
void transpose_v(const u16* __restrict__ qkv, u16* __restrict__ Vg)
{
  const int T = 2048, C3 = 3072;
  const int tblk = blockIdx.x;    // 0..31
  const int bh = blockIdx.y;      // 0..63
  const int b = bh >> 4, h = bh & 15;
  __shared__ u16 tile[64][72];
  const int tid = threadIdx.x;
#pragma unroll
  for (int it = 0; it < 2; ++it) {
    int idx = it * 256 + tid;
    int t = idx >> 3, dc = idx & 7;
    short8 v = *reinterpret_cast<const short8*>(
        &qkv[(size_t)(b * T + tblk * 64 + t) * C3 + 2048 + h * 64 + dc * 8]);
    *reinterpret_cast<short8*>(&tile[t][dc * 8]) = v;
  }
  __syncthreads();
#pragma unroll
  for (int it = 0; it < 2; ++it) {
    int idx = it * 256 + tid;
    int d = idx >> 3, tb = idx & 7;
    short8 v;
#pragma unroll
    for (int i = 0; i < 8; ++i) v[i] = (short)tile[tb * 8 + i][d];
    *reinterpret_cast<short8*>(&Vg[((size_t)bh * 64 + d) * T + (size_t)tblk * 64 + tb * 8]) = v;
  }
}

// ---------------- GEMM: C[M,N] = A[M,K] * Bt[N,K]^T (+bias), bf16 in, fp32 acc ----------------
// 128x128 tile, 4 waves of 64x64, BK=32, global_load_lds staging (m97 structure).
// 1D grid with XCD-aware bijective swizzle (T1): nwg%8==0 for both launches.
// M is fixed at 8192 (64 row tiles) for this problem.
template<bool BIAS, bool BF16_OUT>
__global__ __launch_bounds__(256)
void gemm_bt(const u16* __restrict__ A, const u16* __restrict__ Bt,
             const float* __restrict__ bias, void* __restrict__ Cout,
             int M, int N, int K)
{
  __shared__ u16 As[128 * 32];
  __shared__ u16 Bs[128 * 32];
  const int tid  = threadIdx.x;
  const int wave = tid >> 6, lane = tid & 63;
  const int l15 = lane & 15, l4 = lane >> 4;
  // XCD swizzle: consecutive wg within one XCD -> B-panel stays L2-resident
  const int nwg = gridDim.x, qq = nwg >> 3;
  const int wg = (blockIdx.x & 7) * qq + (blockIdx.x >> 3);
  const int row0 = (wg & 63) * 128, col0 = (wg >> 6) * 128;
  const int wr = (wave >> 1) * 64, wc = (wave & 1) * 64;

  f32x4 acc[4][4] = {};

  const int i0 = tid, i1 = tid + 256;
  const int ar0 = i0 >> 2, ac0 = (i0 & 3) * 8;
  const int ar1 = i1 >> 2, ac1 = (i1 & 3) * 8;

  for (int k0 = 0; k0 < K; k0 += 32) {
    __builtin_amdgcn_global_load_lds(
      (const __attribute__((address_space(1))) void*)(A + (size_t)(row0 + ar0) * K + k0 + ac0),
      (__attribute__((address_space(3))) void*)(As + wave * 512), 16, 0, 0);
    __builtin_amdgcn_global_load_lds(
      (const __attribute__((address_space(1))) void*)(A + (size_t)(row0 + ar1) * K + k0 + ac1),
      (__attribute__((address_space(3))) void*)(As + 2048 + wave * 512), 16, 0, 0);
    __builtin_amdgcn_global_load_lds(
      (const __attribute__((address_space(1))) void*)(Bt + (size_t)(col0 + ar0) * K + k0 + ac0),
      (__attribute__((address_space(3))) void*)(Bs + wave * 512), 16, 0, 0);
    __builtin_amdgcn_global_load_lds(
      (const __attribute__((address_space(1))) void*)(Bt + (size_t)(col0 + ar1) * K + k0 + ac1),
      (__attribute__((address_space(3))) void*)(Bs + 2048 + wave * 512), 16, 0, 0);
    __syncthreads();

    short8 af[4], bfr[4];
#pragma unroll
    for (int m = 0; m < 4; ++m)
      af[m] = *reinterpret_cast<const short8*>(&As[(wr + m * 16 + l15) * 32 + l4 * 8]);
#pragma unroll
    for (int n = 0; n < 4; ++n)
      bfr[n] = *reinterpret_cast<const short8*>(&Bs[(wc + n * 16 + l15) * 32 + l4 * 8]);
#pragma unroll
    for (int m = 0; m < 4; ++m)
#pragma unroll
      for (int n = 0; n < 4; ++n)
        acc[m][n] = __builtin_amdgcn_mfma_f32_16x16x32_bf16(af[m], bfr[n], acc[m][n], 0, 0, 0);
    __syncthreads();
  }

  u16* Cb = (u16*)Cout;
  float* Cf = (float*)Cout;
#pragma unroll
  for (int n = 0; n < 4; ++n) {
    const int c = col0 + wc + n * 16 + l15;
    const float bv = BIAS ? bias[c] : 0.0f;
#pragma unroll
    for (int m = 0; m < 4; ++m) {
      const int r0 = row0 + wr + m * 16 + l4 * 4;
#pragma unroll
      for (int r = 0; r < 4; ++r) {
        float v = acc[m][n][r] + bv;
        if (BF16_OUT) Cb[(size_t)(r0 + r) * N + c] = f2bf(v);
        else          Cf[(size_t)(r0 + r) * N + c] = v;
      }
    }
  }
}

// ---------------- flash attention, swapped-QK in-register softmax ----------------
// 256 thr = 4 waves; wave w owns 32 queries (QBLK=128); KV tiles of 64 (2 x 32 sub-tiles).
// S^T = mfma32x32(K, Q): lane holds 16 score regs for ONE query col (q = lane&31).
// qb from a balance table: under round-robin dispatch CU k's residents draw qb from
// {15,0,14,1}/{13,2,12,3}/{11,4,10,5}/{9,6,8,7} - every set = 68 tile-iters (R13 fix:
// bid&15 stacked 4 same-qb blocks per CU -> 128-iter makespan on qb=15 CUs).
__global__ __launch_bounds__(256, 3)
void attn_kernel(const u16* __restrict__ qkv, const u16* __restrict__ Vg, u16* __restrict__ att)
{
  const int T = 2048, C3 = 3072;
  const int bid = blockIdx.x;
  const int qtbl[16] = {15,13,11,9,0,2,4,6,14,12,10,8,1,3,5,7};
  const int qb = qtbl[bid >> 6];
  const int bh = bid & 63;
  const int b = bh >> 4, h = bh & 15;
  const int tid = threadIdx.x, w = tid >> 6, lane = tid & 63;
  const int l31 = lane & 31, hh = lane >> 5;

  __shared__ u16 sh[2][64][72];       // [0]=K [s][d], [1]=V^T [d][s]; reused by epilogue
  u16 (*Ks)[72] = sh[0];
  u16 (*Vt)[72] = sh[1];

  const size_t base = (size_t)b * T * C3 + (size_t)h * 64;
  const u16* qp  = qkv + base;            // pre-scaled by log2e/32 via repack_w
  const u16* kp  = qkv + base + 1024;
  const u16* vtp = Vg + (size_t)bh * 64 * T;

  // Q B-fragments: B[k=d][col=q], lane: col=l31, k=hh*8+i within d-tile j
  const int q = qb * 128 + w * 32 + l31;
  short8 qf[4];
#pragma unroll
  for (int j = 0; j < 4; ++j)
    qf[j] = *reinterpret_cast<const short8*>(&qp[(size_t)q * C3 + j * 16 + hh * 8]);

  // staging: thread -> row tid>>2, col chunk (tid&3)*16 (two short8 each for K and V^T)
  const int srow = tid >> 2, scc = (tid & 3) * 16;
  short8 kr0 = *reinterpret_cast<const short8*>(&kp[(size_t)srow * C3 + scc]);
  short8 kr1 = *reinterpret_cast<const short8*>(&kp[(size_t)srow * C3 + scc + 8]);
  short8 vr0 = *reinterpret_cast<const short8*>(&vtp[(size_t)srow * T + scc]);
  short8 vr1 = *reinterpret_cast<const short8*>(&vtp[(size_t)srow * T + scc + 8]);

  f32x16 o0 = {}, o1 = {};            // O^T accum: d-tiles 0 (d0..31) and 1 (d32..63)
  float mrun = -1e30f, lrun = 0.0f;

  const int kv_last = 2 * qb + 1;
  const int qmin_w = qb * 128 + w * 32, qmax_w = qmin_w + 31;

  for (int kvb = 0; kvb <= kv_last; ++kvb) {
    __syncthreads();                  // prev tile's readers done
    *reinterpret_cast<short8*>(&Ks[srow][scc])     = kr0;
    *reinterpret_cast<short8*>(&Ks[srow][scc + 8]) = kr1;
    *reinterpret_cast<short8*>(&Vt[srow][scc])     = vr0;
    *reinterpret_cast<short8*>(&Vt[srow][scc + 8]) = vr1;
    __syncthreads();                  // tile visible

    if (kvb < kv_last) {              // prefetch next tile (hides under compute)
      const u16* kn = kp + (size_t)((kvb + 1) * 64 + srow) * C3 + scc;
      kr0 = *reinterpret_cast<const short8*>(kn);
      kr1 = *reinterpret_cast<const short8*>(kn + 8);
      const u16* vn = vtp + (size_t)srow * T + (kvb + 1) * 64 + scc;
      vr0 = *reinterpret_cast<const short8*>(vn);
      vr1 = *reinterpret_cast<const short8*>(vn + 8);
    }

#pragma unroll
    for (int st = 0; st < 2; ++st) {
      const int sbase = kvb * 64 + st * 32;
      if (sbase > qmax_w) continue;   // wave-uniform causal skip

      // S^T = K x Q : D[s][q], lane: q=l31, s-slots (r&3)+8*(r>>2)+4*hh
      f32x16 sc = {};
#pragma unroll
      for (int j = 0; j < 4; ++j) {
        short8 ka = *reinterpret_cast<const short8*>(&Ks[st * 32 + l31][j * 16 + hh * 8]);
        sc = __builtin_amdgcn_mfma_f32_32x32x16_bf16(ka, qf[j], sc, 0, 0, 0);
      }

      if (sbase + 31 > qmin_w) {      // diagonal overlap -> causal mask
#pragma unroll
        for (int r = 0; r < 16; ++r) {
          int sg = sbase + (r & 3) + 8 * (r >> 2) + 4 * hh;
          if (sg > q) sc[r] = -1e30f;
        }
      }

      // column (per-query) max: in-lane tree over 16 slots + cross-half shfl
      float a0 = fmaxf(sc[0], sc[1]),  a1 = fmaxf(sc[2], sc[3]);
      float a2 = fmaxf(sc[4], sc[5]),  a3 = fmaxf(sc[6], sc[7]);
      float a4 = fmaxf(sc[8], sc[9]),  a5 = fmaxf(sc[10], sc[11]);
      float a6 = fmaxf(sc[12], sc[13]), a7 = fmaxf(sc[14], sc[15]);
      a0 = fmaxf(a0, a1); a2 = fmaxf(a2, a3); a4 = fmaxf(a4, a5); a6 = fmaxf(a6, a7);
      a0 = fmaxf(a0, a2); a4 = fmaxf(a4, a6);
      float mt = fmaxf(a0, a4);
      mt = fmaxf(mt, __shfl_xor(mt, 32));

      float mn = fmaxf(mrun, mt);
      float alpha = __builtin_exp2f(mrun - mn);
      mrun = mn;

      float p[16];
#pragma unroll
      for (int r = 0; r < 16; ++r) p[r] = __builtin_exp2f(sc[r] - mn);
      float s0 = (p[0] + p[1]) + (p[2] + p[3]);
      float s1 = (p[4] + p[5]) + (p[6] + p[7]);
      float s2 = (p[8] + p[9]) + (p[10] + p[11]);
      float s3 = (p[12] + p[13]) + (p[14] + p[15]);
      float rs = (s0 + s1) + (s2 + s3);
      rs += __shfl_xor(rs, 32);

      lrun = lrun * alpha + rs;
      o0 = o0 * alpha;
      o1 = o1 * alpha;

      // pack P^T into PV B-fragment dwords.
      // own slots (r=0..7):  c0={s 0+4hh,1+4hh} c1={2+4hh,3+4hh} c2={8+4hh,9+4hh} c3={10+4hh,11+4hh}
      // B-frag needs k = hh*8 + {0..7}:
      //   hh=0: {c0, c1, partner c0, partner c1}
      //   hh=1: {partner c2, partner c3, c2, c3}
      unsigned c0 = cvtpk(p[0], p[1]),   c1 = cvtpk(p[2], p[3]);
      unsigned c2 = cvtpk(p[4], p[5]),   c3 = cvtpk(p[6], p[7]);
      unsigned c4 = cvtpk(p[8], p[9]),   c5 = cvtpk(p[10], p[11]);
      unsigned c6 = cvtpk(p[12], p[13]), c7 = cvtpk(p[14], p[15]);
      unsigned x0 = __shfl_xor(c0, 32), x1 = __shfl_xor(c1, 32);
      unsigned x2 = __shfl_xor(c2, 32), x3 = __shfl_xor(c3, 32);
      unsigned x4 = __shfl_xor(c4, 32), x5 = __shfl_xor(c5, 32);
      unsigned x6 = __shfl_xor(c6, 32), x7 = __shfl_xor(c7, 32);
      union PU { unsigned u[4]; short8 s8; };
      PU pu0, pu1;
      pu0.u[0] = hh ? x2 : c0;  pu0.u[1] = hh ? x3 : c1;
      pu0.u[2] = hh ? c2 : x0;  pu0.u[3] = hh ? c3 : x1;
      pu1.u[0] = hh ? x6 : c4;  pu1.u[1] = hh ? x7 : c5;
      pu1.u[2] = hh ? c6 : x4;  pu1.u[3] = hh ? c7 : x5;

      // O^T += V^T x P^T
#pragma unroll
      for (int sm = 0; sm < 2; ++sm) {
        short8 pb = sm ? pu1.s8 : pu0.s8;
        short8 va0 = *reinterpret_cast<const short8*>(&Vt[l31][st * 32 + sm * 16 + hh * 8]);
        o0 = __builtin_amdgcn_mfma_f32_32x32x16_bf16(va0, pb, o0, 0, 0, 0);
        short8 va1 = *reinterpret_cast<const short8*>(&Vt[32 + l31][st * 32 + sm * 16 + hh * 8]);
        o1 = __builtin_amdgcn_mfma_f32_32x32x16_bf16(va1, pb, o1, 0, 0, 0);
      }
    }
  }

  // epilogue: normalize, LDS transpose (per-wave region), coalesced store
  __syncthreads();                    // all waves done reading Ks/Vt
  const float inv = 1.0f / lrun;
  u16* ep = (u16*)sh + w * 2304 + l31 * 72;   // [32 q][72] per wave
#pragma unroll
  for (int k = 0; k < 8; ++k) {
    const int d0 = ((k & 1) * 2) + ((k >> 1) * 8) + 4 * hh;
    *reinterpret_cast<unsigned*>(&ep[d0])      = cvtpk(o0[2 * k] * inv, o0[2 * k + 1] * inv);
    *reinterpret_cast<unsigned*>(&ep[32 + d0]) = cvtpk(o1[2 * k] * inv, o1[2 * k + 1] * inv);
  }
  __syncthreads();
  const int rr = lane >> 1, cc0 = (lane & 1) * 32;
  const u16* epw = (u16*)sh + w * 2304 + rr * 72 + cc0;
  u16* op = att + (size_t)(b * T + qb * 128 + w * 32 + rr) * 1024 + h * 64 + cc0;
#pragma unroll
  for (int c = 0; c < 4; ++c)
    *reinterpret_cast<short8*>(&op[c * 8]) = *reinterpret_cast<const short8*>(&epw[c * 8]);
}

// ---------------- launch ----------------
extern "C" void kernel_launch(void* const* d_in, const int* in_sizes, int n_in,
                              void* d_out, int out_size, void* d_ws, size_t ws_size,
                              hipStream_t stream)
{
  const float* x  = (const float*)d_in[0];
  const float* wq = (const float*)d_in[1];
  const float* wk = (const float*)d_in[2];
  const float* wv = (const float*)d_in[3];
  const float* wp = (const float*)d_in[4];
  const float* bp = (const float*)d_in[5];
  float* out = (float*)d_out;

  u16* xb  = (u16*)d_ws;                       // 8192*1024 (dead after QKV gemm)
  u16* Wt  = xb  + (size_t)8192 * 1024;        // 3072*1024
  u16* wpb = Wt  + (size_t)3072 * 1024;        // 1024*1024
  u16* QKV = wpb + (size_t)1024 * 1024;        // 8192*3072
  u16* att = QKV + (size_t)8192 * 3072;        // 8192*1024
  u16* Vg  = xb;                               // alias: V^T [64 bh][64 d][2048 t]
  // total ws: 46.1M u16 = 92.3 MB

  cvt_f32_bf16<<<8192, 256, 0, stream>>>(x, xb);
  cvt_f32_bf16<<<1024, 256, 0, stream>>>(wp, wpb);
  repack_w<<<3072, 256, 0, stream>>>(wq, wk, wv, Wt);
  gemm_bt<false, true><<<1536, 256, 0, stream>>>(xb, Wt, nullptr, QKV, 8192, 3072, 1024);
  transpose_v<<<dim3(32, 64), 256, 0, stream>>>(QKV, Vg);
  attn_kernel<<<1024, 256, 0, stream>>>(QKV, Vg, att);
  gemm_bt<true, false><<<512, 256, 0, stream>>>(att, wpb, bp, out, 8192, 1024, 1024);
}